// Round 4
// baseline (158.595 us; speedup 1.0000x reference)
//
#include <hip/hip_runtime.h>
#include <math.h>

#define GRID_CELLS 49
#define NOBJ 10
#define BB 2
#define NCLS 20
#define OUT_C 30   // 5*BB + NCLS
#define LAMBDA_C 5.0f
#define LAMBDA_N 0.5f
#define BLOCK 256

// One thread per (batch_item, grid_cell). Streaming loads, low VGPR.
__global__ __launch_bounds__(BLOCK, 4) void yolo_loss_flat(
    const float* __restrict__ outputs,
    const float* __restrict__ target,
    float* __restrict__ out,
    int batch, float inv_batch)
{
    const int gid = blockIdx.x * BLOCK + threadIdx.x;
    float lsum = 0.0f;

    if (gid < batch * GRID_CELLS) {
        const int b = gid / GRID_CELLS;
        const int c = gid - b * GRID_CELLS;

        // ---- phase 1: build gt[2][5] for this cell, streaming 2 objects
        //      per 5 float2 loads (base b*200B is 8-aligned) ----
        float g0[5] = {0.f, 0.f, 0.f, 0.f, 0.f};
        float g1[5] = {0.f, 0.f, 0.f, 0.f, 0.f};
        int cnt = 0;
        const float2* t2 = reinterpret_cast<const float2*>(target + (size_t)b * (NOBJ * 5));
        #pragma unroll
        for (int i = 0; i < 5; ++i) {
            float2 a0 = t2[5 * i + 0];
            float2 a1 = t2[5 * i + 1];
            float2 a2 = t2[5 * i + 2];
            float2 a3 = t2[5 * i + 3];
            float2 a4 = t2[5 * i + 4];
            float v[10] = {a0.x, a0.y, a1.x, a1.y, a2.x, a2.y, a3.x, a3.y, a4.x, a4.y};
            #pragma unroll
            for (int h = 0; h < 2; ++h) {
                float t0 = v[5 * h + 0];
                float t1 = v[5 * h + 1];
                float t2f = sqrtf(v[5 * h + 2]);
                float t3f = sqrtf(v[5 * h + 3]);
                float t4 = v[5 * h + 4];
                if (t0 != t0)  t0  = -1.0f;
                if (t1 != t1)  t1  = -1.0f;
                if (t2f != t2f) t2f = -1.0f;
                if (t3f != t3f) t3f = -1.0f;
                if (t4 != t4)  t4  = -1.0f;
                int xi = (int)truncf(7.0f * t0);
                int yi = (int)truncf(7.0f * t1);
                int cell = 7 * yi + xi;
                cell = cell < 0 ? 0 : (cell > GRID_CELLS - 1 ? GRID_CELLS - 1 : cell);
                bool valid = (t0 != -1.0f) && (xi >= 0);
                float s5 = t0 + t1 + t2f + t3f + t4;
                if (valid && (s5 > 0.0f) && cell == c) {
                    if (cnt == 0)      { g0[0]=t0; g0[1]=t1; g0[2]=t2f; g0[3]=t3f; g0[4]=t4; }
                    else if (cnt == 1) { g1[0]=t0; g1[1]=t1; g1[2]=t2f; g1[3]=t3f; g1[4]=t4; }
                    ++cnt;
                }
            }
        }
        float g[BB][5];
        #pragma unroll
        for (int d = 0; d < 5; ++d) { g[0][d] = g0[d]; g[1][d] = g1[d]; }

        // ---- phase 2: pred boxes (5 float2) + streaming class scan (10 float2) ----
        const float2* r2 = reinterpret_cast<const float2*>(outputs + (size_t)gid * OUT_C);
        float pred[BB][5];
        {
            float2 p0 = r2[0], p1 = r2[1], p2 = r2[2], p3 = r2[3], p4 = r2[4];
            pred[0][0] = p0.x; pred[0][1] = p0.y; pred[0][2] = p1.x; pred[0][3] = p1.y; pred[0][4] = p2.x;
            pred[1][0] = p2.y; pred[1][1] = p3.x; pred[1][2] = p3.y; pred[1][3] = p4.x; pred[1][4] = p4.y;
        }
        float maxp; int cls;
        {
            float2 q0 = r2[5];
            maxp = q0.x; cls = 0;
            if (q0.y > maxp) { maxp = q0.y; cls = 1; }
            #pragma unroll
            for (int i = 1; i < NCLS / 2; ++i) {
                float2 q = r2[5 + i];
                if (q.x > maxp) { maxp = q.x; cls = 2 * i; }
                if (q.y > maxp) { maxp = q.y; cls = 2 * i + 1; }
            }
        }
        float fcls = (float)cls;

        // pred boxes (sqrt-then-square, matching reference bit behavior)
        float pminx[BB], pmaxx[BB], pminy[BB], pmaxy[BB], parea[BB];
        #pragma unroll
        for (int p = 0; p < BB; ++p) {
            float sw = sqrtf(pred[p][2]);
            float sh = sqrtf(pred[p][3]);
            float w2 = sw * sw, h2 = sh * sh;
            pminx[p] = pred[p][0] - w2; pmaxx[p] = pred[p][0] + w2;
            pminy[p] = pred[p][1] - h2; pmaxy[p] = pred[p][1] + h2;
            parea[p] = fabsf(pmaxx[p] - pminx[p]) * fabsf(pmaxy[p] - pminy[p]);
        }
        float gminx[BB], gmaxx[BB], gminy[BB], gmaxy[BB], garea[BB];
        #pragma unroll
        for (int s = 0; s < BB; ++s) {
            float w2 = g[s][2] * g[s][2], h2 = g[s][3] * g[s][3];
            gminx[s] = g[s][0] - w2; gmaxx[s] = g[s][0] + w2;
            gminy[s] = g[s][1] - h2; gmaxy[s] = g[s][1] + h2;
            garea[s] = fabsf(gmaxx[s] - gminx[s]) * fabsf(gmaxy[s] - gminy[s]);
        }
        // t_index[s] = argmax_p iou[p][s] (first max on ties, as jnp.argmax)
        int t_index[BB];
        #pragma unroll
        for (int s = 0; s < BB; ++s) {
            float best = 0.0f; int bi = 0;
            #pragma unroll
            for (int p = 0; p < BB; ++p) {
                float ix0 = fmaxf(gminx[s], pminx[p]);
                float iy0 = fmaxf(gminy[s], pminy[p]);
                float ix1 = fminf(gmaxx[s], pmaxx[p]);
                float iy1 = fminf(gmaxy[s], pmaxy[p]);
                float dx = fmaxf(ix1 - ix0, 0.0f);
                float dy = fmaxf(iy1 - iy0, 0.0f);
                float inter = dx * dy;
                float uni = garea[s] + parea[p] - inter;
                float iou = (uni == 0.0f) ? 0.0f : inter / uni;
                if (p == 0) { best = iou; bi = 0; }
                else if (iou > best) { best = iou; bi = p; }
            }
            t_index[s] = bi;
        }

        #pragma unroll
        for (int s = 0; s < BB; ++s) {
            float ga[5];
            #pragma unroll
            for (int d = 0; d < 5; ++d) ga[d] = (t_index[s] == 0) ? g[0][d] : g[1][d];
            // conf (trunc-based IoU of raw boxes)
            float r1w = pred[s][2] * pred[s][2], r1h = pred[s][3] * pred[s][3];
            float r2w = ga[2] * ga[2],           r2h = ga[3] * ga[3];
            float min1x = pred[s][0] - 0.5f * r1w, max1x = pred[s][0] + 0.5f * r1w;
            float min1y = pred[s][1] - 0.5f * r1h, max1y = pred[s][1] + 0.5f * r1h;
            float min2x = ga[0] - 0.5f * r2w, max2x = ga[0] + 0.5f * r2w;
            float min2y = ga[1] - 0.5f * r2h, max2y = ga[1] + 0.5f * r2h;
            float dx = fmaxf(fminf(max1x, max2x) - fmaxf(min1x, min2x), 0.0f);
            float dy = fmaxf(fminf(max1y, max2y) - fmaxf(min1y, min2y), 0.0f);
            float inter2 = dx * dy;
            float uni2 = r1w * r1h + r2w * r2h - inter2;
            float conf;
            if (truncf(uni2) == 0.0f || truncf(inter2) == 0.0f) conf = 0.0f;
            else conf = truncf(inter2 / (uni2 == 0.0f ? 1.0f : uni2));
            // obj loss: w=[5,5,5,5,1] * (final_gt - pred5)^2
            #pragma unroll
            for (int d = 0; d < 4; ++d) {
                float df = ga[d] - pred[s][d];
                lsum += LAMBDA_C * df * df;
            }
            { float df = conf - pred[s][4]; lsum += df * df; }
            // noobj loss (mask quirk: last batch item, slot t_index[BB-1] zeroed)
            float m = 1.0f;
            if (b == batch - 1 && s == t_index[BB - 1]) m = 0.0f;
            float dn = (pred[s][4] - conf) * m;
            lsum += LAMBDA_N * dn * dn;
            // class loss
            float predn = maxp * pred[s][4];
            float truth = (conf == fcls) ? 1.0f : 0.0f;
            float sum5 = ga[0] + ga[1] + ga[2] + ga[3] + conf;
            float cm = (sum5 > 0.0f) ? 1.0f : ((sum5 < 0.0f) ? -1.0f : 0.0f);
            float dcl = truth - predn;
            lsum += cm * dcl * dcl;
        }
    }

    // ---- block reduction: wave shuffle -> LDS -> one atomic per block ----
    #pragma unroll
    for (int off = 32; off > 0; off >>= 1) lsum += __shfl_down(lsum, off, 64);
    __shared__ float red[BLOCK / 64];
    const int wid = threadIdx.x >> 6;
    const int lane = threadIdx.x & 63;
    if (lane == 0) red[wid] = lsum;
    __syncthreads();
    if (threadIdx.x == 0) {
        float s = 0.0f;
        #pragma unroll
        for (int w = 0; w < BLOCK / 64; ++w) s += red[w];
        atomicAdd(out, s * inv_batch);
    }
}

extern "C" void kernel_launch(void* const* d_in, const int* in_sizes, int n_in,
                              void* d_out, int out_size, void* d_ws, size_t ws_size,
                              hipStream_t stream) {
    const float* outputs = (const float*)d_in[0];
    const float* target  = (const float*)d_in[1];
    float* out = (float*)d_out;
    int batch = in_sizes[1] / (NOBJ * 5);   // 16384
    int total = batch * GRID_CELLS;
    int nblocks = (total + BLOCK - 1) / BLOCK;   // 3136
    hipMemsetAsync(out, 0, sizeof(float), stream);
    yolo_loss_flat<<<nblocks, BLOCK, 0, stream>>>(outputs, target, out, batch, 1.0f / (float)batch);
}